// Round 6
// baseline (314.415 us; speedup 1.0000x reference)
//
#include <hip/hip_runtime.h>
#include <hip/hip_fp16.h>

// GRU cell, B=65536, 256 inputs, 256 hidden, fp32 in/out.
// R9: persistent 2-tile pipeline. R8 (clean: VGPR 84, no spills) proved the
// 4-independent-blocks desync theory NEUTRAL (133 vs 136us): identical blocks
// dispatched together CONVOY through resource contention -- phases add
// (stage HBM + pass1 + epi1 + pass2 + epi2/store, x2 generations) and
// occupancy can't break the symmetry. R4's +220MB spill traffic costing only
// +3us rules out load-latency as the dominant stall. So: eliminate the
// generation boundary structurally. Grid = 1024 persistent blocks (exactly
// 4/CU), each runs 2 row-tiles; tile-1's x staged into lx DURING tile-0's
// pass-2 back half (lx is dead after pass-2 s==8 barrier -- same liveness
// trick as the epi1 barrier move), h staged after pass-2 under epi2. The
// next tile's HBM staging hides entirely under MFMA+epilogue instead of
// serializing chip-wide.
// Also: NT stores dropped -- R8 measured WRITE 164MB vs 131 ideal (NT defeats
// L2 write-combining; MT=32 waves cover only 64B/row fragments). Plain
// stores restore full-line merging.
// Retained: MT=32, 4 waves, CPW=4, RT=2, 32KB LDS; coltile-pair micro-step
// weight dbuf; lgkm-only barriers (no vmcnt drains in body); setprio around
// MFMA clusters; __launch_bounds__(256,2) -> measured VGPR cap 128 (rule:
// cap = 512/(2*arg2), verified R4/R6/R8).

#define NHID 256
#define B_ROWS 65536
#define MT 32                        // rows per tile
#define RT 2                         // row tiles per wave (MT/16)
#define CPW 4                        // coltiles per wave (16 coltiles / 4 waves)
#define NBLK 1024                    // persistent blocks; tiles = bid, bid+NBLK
#define GATE_STRIDE (16 * 16 * 64 * 8)   // halves per packed gate

typedef _Float16 half8 __attribute__((ext_vector_type(8)));
typedef _Float16 half4_t __attribute__((ext_vector_type(4)));
typedef _Float16 half2_t __attribute__((ext_vector_type(2)));
typedef float floatx4 __attribute__((ext_vector_type(4)));

// LDS layout for lx/lh: row-major [MT][256] halves, 8-half-chunk XOR swizzle
__device__ __forceinline__ int lidx(int m, int c) {
    return m * 256 + ((((c >> 3) ^ (m & 7)) << 3)) + (c & 7);
}

// Workgroup barrier that waits only on LDS ops (lgkmcnt), NOT vmcnt -- keeps
// prefetched/staged global loads in flight across phase boundaries.
__device__ __forceinline__ void barrier_lgkm() {
    __builtin_amdgcn_sched_barrier(0);
    asm volatile("s_waitcnt lgkmcnt(0)" ::: "memory");
    __builtin_amdgcn_s_barrier();
    __builtin_amdgcn_sched_barrier(0);
}

// ---------- weight packing: B-fragment layout for mfma_f32_16x16x32_f16 ----
// frag (gate g, coltile ct, ktile s): lane holds B[k=s*32+(lane>>4)*8+j][n=ct*16+(lane&15)]
__global__ __launch_bounds__(256) void pack_weights_kernel(
    const float* __restrict__ Wz, const float* __restrict__ Uz,
    const float* __restrict__ Wr, const float* __restrict__ Ur,
    const float* __restrict__ Wh, const float* __restrict__ Uh,
    _Float16* __restrict__ packed)
{
    int tid = blockIdx.x * blockDim.x + threadIdx.x;  // 0..49151
    int lane = tid & 63;
    int s    = (tid >> 6) & 15;
    int ct   = (tid >> 10) & 15;
    int g    = tid >> 14;  // 0:z 1:r 2:h
    const float* W = (g == 0) ? Wz : (g == 1) ? Wr : Wh;
    const float* U = (g == 0) ? Uz : (g == 1) ? Ur : Uh;
    int n  = ct * 16 + (lane & 15);
    int k0 = s * 32 + (lane >> 4) * 8;
    half8 v;
#pragma unroll
    for (int j = 0; j < 8; ++j) {
        int k = k0 + j;
        float f = (k < 256) ? W[k * 256 + n] : U[(k - 256) * 256 + n];
        v[j] = (_Float16)f;
    }
    *reinterpret_cast<half8*>(packed + (size_t)tid * 8) = v;
}

// fragment load for (gate base, coltile ct, ktile s)
#define WFRAG(base, ct, s) \
    (*reinterpret_cast<const half8*>((base) + (size_t)((((ct) * 16 + (s)) * 64 + lane) * 8)))

// ---------- main fused GRU kernel ----------
__global__ __launch_bounds__(256, 2) void gru_main_kernel(
    const float* __restrict__ x, const float* __restrict__ h,
    const _Float16* __restrict__ wpack,
    const float* __restrict__ bz, const float* __restrict__ br,
    const float* __restrict__ bh,
    float* __restrict__ out)
{
    // 32 KB: lx[32*256] + lh[32*256] halves -> 4 blocks/CU (128 KB of 160 KB)
    __shared__ __align__(16) _Float16 lsm[MT * 256 * 2];
    _Float16* lx = lsm;
    _Float16* lh = lsm + MT * 256;

    const int tid  = threadIdx.x;
    const int lane = tid & 63;
    const int wave = tid >> 6;        // 0..3, owns coltiles wave*4 .. wave*4+3
    const int m_lo = lane & 15;
    const int quad = lane >> 4;
    const int mx   = m_lo & 7;
    const int ct0  = wave * CPW;
    const int sc   = (tid & 63) * 4;  // staging column (4 floats / thread / row)

    const _Float16* wz = wpack;
    const _Float16* wr = wpack + GATE_STRIDE;
    const _Float16* wh = wpack + 2 * GATE_STRIDE;
    const float4* xv4 = reinterpret_cast<const float4*>(x);
    const float4* hv4 = reinterpret_cast<const float4*>(h);

    // staging write: row m = it*4 + wave, cols sc..sc+3, fp32->fp16
    auto stage_wr = [&](_Float16* dst, const float4& v, int it) {
        const int m = it * 4 + wave;
        half4_t p = { (_Float16)v.x, (_Float16)v.y, (_Float16)v.z, (_Float16)v.w };
        *reinterpret_cast<half4_t*>(&dst[lidx(m, sc)]) = p;
    };

    // ---- biases: once for both tiles ----
    float bzv[CPW], brv[CPW], bhv[CPW];
#pragma unroll
    for (int c = 0; c < CPW; ++c) {
        const int col = (ct0 + c) * 16 + m_lo;
        bzv[c] = bz[col];
        brv[c] = br[col];
        bhv[c] = bh[col];
    }

    // ---- prefetch pass-1 micro-step-0 weight frags (fly under staging) ----
    half8 wzb[2][2], wrb[2][2];
    wzb[0][0] = WFRAG(wz, ct0 + 0, 0);
    wzb[0][1] = WFRAG(wz, ct0 + 1, 0);
    wrb[0][0] = WFRAG(wr, ct0 + 0, 0);
    wrb[0][1] = WFRAG(wr, ct0 + 1, 0);

    // ---- prologue: stage tile 0 (the only fully exposed staging) ----
    {
        const size_t ib = (size_t)(blockIdx.x * MT) * 64 + tid;  // float4 idx
#pragma unroll
        for (int it = 0; it < 8; ++it) {
            float4 a = xv4[ib + it * 256];
            float4 b = hv4[ib + it * 256];
            stage_wr(lx, a, it);
            stage_wr(lh, b, it);
        }
    }
    barrier_lgkm();

    const size_t OUT2 = (size_t)B_ROWS * NHID;

#pragma unroll
    for (int tile = 0; tile < 2; ++tile) {
        const int row0   = (blockIdx.x + tile * NBLK) * MT;   // this tile
        const size_t nib = (size_t)((blockIdx.x + NBLK) * MT) * 64 + tid; // next

        // packed (z*h, 1-z) per output element, fp16x2
        half2_t zpk[CPW][RT][4];

        // ---- pass 1: Sz = [x|h]@[Wz;Uz], Sr = [x|h]@[Wr;Ur]  (K=512) ----
        floatx4 accz[CPW][RT];
        floatx4 accr[CPW][RT];
#pragma unroll
        for (int c = 0; c < CPW; ++c)
#pragma unroll
            for (int rt = 0; rt < RT; ++rt) {
                accz[c][rt] = (floatx4){0.f, 0.f, 0.f, 0.f};
                accr[c][rt] = (floatx4){0.f, 0.f, 0.f, 0.f};
            }

#pragma unroll
        for (int s = 0; s < 16; ++s) {
            // tile 1: prev transition's lh (h) writes become visible here;
            // s<8 reads only lx (written before the post-pass-2 barrier).
            if (tile == 1 && s == 8) barrier_lgkm();
            const _Float16* asrc = (s < 8) ? lx : lh;
            const int kcx = (((s & 7) * 4 + quad) ^ mx) << 3;
            half8 af[RT];
#pragma unroll
            for (int rt = 0; rt < RT; ++rt)
                af[rt] = *reinterpret_cast<const half8*>(&asrc[(rt * 16 + m_lo) * 256 + kcx]);
#pragma unroll
            for (int p = 0; p < 2; ++p) {
                const int u = s * 2 + p;               // micro-step 0..31
                if (u < 31) {
                    const int ns = (p == 1) ? s + 1 : s;
                    const int nc = ct0 + (p ^ 1) * 2;  // next pair's coltiles
                    wzb[p ^ 1][0] = WFRAG(wz, nc + 0, ns);
                    wzb[p ^ 1][1] = WFRAG(wz, nc + 1, ns);
                    wrb[p ^ 1][0] = WFRAG(wr, nc + 0, ns);
                    wrb[p ^ 1][1] = WFRAG(wr, nc + 1, ns);
                }
                __builtin_amdgcn_s_setprio(1);
#pragma unroll
                for (int q = 0; q < 2; ++q) {
                    const int c = p * 2 + q;
#pragma unroll
                    for (int rt = 0; rt < RT; ++rt) {
                        accz[c][rt] = __builtin_amdgcn_mfma_f32_16x16x32_f16(af[rt], wzb[p][q], accz[c][rt], 0, 0, 0);
                        accr[c][rt] = __builtin_amdgcn_mfma_f32_16x16x32_f16(af[rt], wrb[p][q], accr[c][rt], 0, 0, 0);
                    }
                }
                __builtin_amdgcn_s_setprio(0);
            }
        }

        // pass-2 step-0 weights: in flight through epilogue 1
        half8 whb[2][2];
        whb[0][0] = WFRAG(wh, ct0 + 0, 0);
        whb[0][1] = WFRAG(wh, ct0 + 1, 0);

        barrier_lgkm();  // all waves done reading lh (pass 1) before r*h write

        // ---- epilogue 1: z, r; lh <- r*h; zpk <- (fp16)(z*h, 1-z) ----
        // C layout: col(tile) = lane&15, row(tile) = quad*4 + reg
#pragma unroll
        for (int c = 0; c < CPW; ++c) {
#pragma unroll
            for (int rt = 0; rt < RT; ++rt) {
#pragma unroll
                for (int e = 0; e < 4; ++e) {
                    const int row = rt * 16 + quad * 4 + e;
                    const int col = (ct0 + c) * 16 + m_lo;
                    float sz = accz[c][rt][e] + bzv[c];
                    float sr = accr[c][rt][e] + brv[c];
                    float zv = 1.f / (1.f + __expf(-sz));
                    float rv = 1.f / (1.f + __expf(-sr));
                    const int li = lidx(row, col);
                    float hval = (float)lh[li];
                    lh[li] = (_Float16)(rv * hval);
                    zpk[c][rt][e] = half2_t{ (_Float16)(zv * hval), (_Float16)(1.f - zv) };
                }
            }
        }
        // NO barrier here: pass-2 s<8 reads only lx; lh barrier is at s==8.

        // ---- pass 2: Sh = [x|r*h]@[Wh;Uh]  (K=512) + pipelined x staging ----
        floatx4 acch[CPW][RT];
#pragma unroll
        for (int c = 0; c < CPW; ++c)
#pragma unroll
            for (int rt = 0; rt < RT; ++rt)
                acch[c][rt] = (floatx4){0.f, 0.f, 0.f, 0.f};

        float4 xra[4], xrb[4], hr[8];

#pragma unroll
        for (int s = 0; s < 16; ++s) {
            if (s == 8) {
                barrier_lgkm();  // r*h visible; lx now dead for this tile
                if (tile == 0) {
#pragma unroll
                    for (int it = 0; it < 4; ++it)
                        xra[it] = xv4[nib + it * 256];
                }
            }
            if (s == 12 && tile == 0) {
                // xra landed (4 usteps of cover); write into dead lx, fetch xrb
#pragma unroll
                for (int it = 0; it < 4; ++it) stage_wr(lx, xra[it], it);
#pragma unroll
                for (int it = 0; it < 4; ++it)
                    xrb[it] = xv4[nib + (it + 4) * 256];
            }
            const _Float16* asrc = (s < 8) ? lx : lh;
            const int kcx = (((s & 7) * 4 + quad) ^ mx) << 3;
            half8 af[RT];
#pragma unroll
            for (int rt = 0; rt < RT; ++rt)
                af[rt] = *reinterpret_cast<const half8*>(&asrc[(rt * 16 + m_lo) * 256 + kcx]);
#pragma unroll
            for (int p = 0; p < 2; ++p) {
                const int u = s * 2 + p;
                if (u < 31) {
                    const int ns = (p == 1) ? s + 1 : s;
                    const int nc = ct0 + (p ^ 1) * 2;
                    whb[p ^ 1][0] = WFRAG(wh, nc + 0, ns);
                    whb[p ^ 1][1] = WFRAG(wh, nc + 1, ns);
                }
                __builtin_amdgcn_s_setprio(1);
#pragma unroll
                for (int q = 0; q < 2; ++q) {
                    const int c = p * 2 + q;
#pragma unroll
                    for (int rt = 0; rt < RT; ++rt)
                        acch[c][rt] = __builtin_amdgcn_mfma_f32_16x16x32_f16(af[rt], whb[p][q], acch[c][rt], 0, 0, 0);
                }
                __builtin_amdgcn_s_setprio(0);
            }
        }

        if (tile == 0) {
            // finish x staging; launch h loads (hide under epi2); reload
            // pass-1 step-0 weight frags for tile 1.
#pragma unroll
            for (int it = 0; it < 4; ++it) stage_wr(lx, xrb[it], it + 4);
#pragma unroll
            for (int it = 0; it < 8; ++it) hr[it] = hv4[nib + it * 256];
            wzb[0][0] = WFRAG(wz, ct0 + 0, 0);
            wzb[0][1] = WFRAG(wz, ct0 + 1, 0);
            wrb[0][0] = WFRAG(wr, ct0 + 0, 0);
            wrb[0][1] = WFRAG(wr, ct0 + 1, 0);
        }

        barrier_lgkm();  // all pass-2 lh reads done; all x writes done

        // ---- epilogue 2: h_t = z*h + (1-z)*tanh(Sh+bh) -> plain stores ----
        // Plain (non-NT) stores: L2 write-combines the 64B fragments into
        // full lines (R8: NT gave WRITE 164MB vs 131 ideal).
#pragma unroll
        for (int c = 0; c < CPW; ++c) {
            const int col = (ct0 + c) * 16 + m_lo;
#pragma unroll
            for (int rt = 0; rt < RT; ++rt) {
#pragma unroll
                for (int e = 0; e < 4; ++e) {
                    const int row = rt * 16 + quad * 4 + e;
                    float sh = acch[c][rt][e] + bhv[c];
                    float e2 = __expf(2.f * sh);
                    float hh = 1.f - 2.f / (e2 + 1.f);  // tanh
                    float zh  = (float)zpk[c][rt][e][0];
                    float omz = (float)zpk[c][rt][e][1];
                    float ht  = zh + omz * hh;
                    size_t idx = (size_t)(row0 + row) * NHID + col;
                    out[idx] = ht;
                    out[OUT2 + idx] = ht;
                }
            }
        }

        if (tile == 0) {
            // h staging for tile 1 (loads have been in flight through epi2);
            // visibility guaranteed by tile-1 pass-1's s==8 barrier.
#pragma unroll
            for (int it = 0; it < 8; ++it) stage_wr(lh, hr[it], it);
        }
    }
}

extern "C" void kernel_launch(void* const* d_in, const int* in_sizes, int n_in,
                              void* d_out, int out_size, void* d_ws, size_t ws_size,
                              hipStream_t stream) {
    (void)in_sizes; (void)n_in; (void)out_size; (void)ws_size;
    const float* x  = (const float*)d_in[0];
    const float* h  = (const float*)d_in[1];
    const float* Wz = (const float*)d_in[2];
    const float* Uz = (const float*)d_in[3];
    const float* bz = (const float*)d_in[4];
    const float* Wr = (const float*)d_in[5];
    const float* Ur = (const float*)d_in[6];
    const float* br = (const float*)d_in[7];
    const float* Wh = (const float*)d_in[8];
    const float* Uh = (const float*)d_in[9];
    const float* bh = (const float*)d_in[10];
    float* out = (float*)d_out;
    _Float16* wpack = (_Float16*)d_ws;  // 3*512*256*2 = 768 KB

    pack_weights_kernel<<<192, 256, 0, stream>>>(Wz, Uz, Wr, Ur, Wh, Uh, wpack);
    gru_main_kernel<<<NBLK, 256, 0, stream>>>(x, h, wpack, bz, br, bh, out);
}

// Round 7
// 303.995 us; speedup vs baseline: 1.0343x; 1.0343x over previous
//
#include <hip/hip_runtime.h>
#include <hip/hip_fp16.h>

// GRU cell, B=65536, 256 inputs, 256 hidden, fp32 in/out.
// R10 = R8 (best, 133us clean) + ONE change: epilogue-1 fused into pass-2's
// first 8 s-steps (4 output elements per step). Rationale: phases serialize
// (no pipe >29% while dur = 3.3x the streaming floor); R8 proved block-level
// desync neutral and R9 proved reg-staged pipelining regresses (64 VGPR of
// payload -> cap/spills). The remaining overlap mechanism needs no desync
// and no payload: VALU/TRANS co-issues with MFMA inside one wave's stream
// (m114). Pass-2 s<8 reads only lx; epi1 writes lh(r*h)/zpk consumed at
// s>=8 / epi2. Slicing epi1 across s=0..7 puts the sigmoid bursts under the
// MFMA clusters; the existing s==8 barrier already gives exactly the
// required cross-wave visibility (no wave passes s==8 until all waves have
// finished their slices). Barrier count/positions unchanged from R8.
// Register budget at pass-2 s~0: accz+accr(32, dying) + acch(32) + whb(16)
// + af(8) + zpk(8) + biases(12) + addr ~= 115 <= 128 -> 4 waves/SIMD kept
// (m69 ladder: 8 waves @ <=64 regs, 4 @ <=128, 2 @ <=256).
// Retained from R8: MT=32, 4 waves, CPW=4, RT=2, 32KB LDS, 2048 blocks;
// coltile-pair micro-step weight dbuf; lgkm-only barriers; step-0 weight
// prefetch before staging; whb/bias prefetch before the post-pass1 barrier;
// NT epilogue-2 stores (R8 vs R9: NT vs plain = identical WRITE_SIZE);
// setprio around MFMA clusters; __launch_bounds__(256,2) -> VGPR cap 128.

#define NHID 256
#define B_ROWS 65536
#define MT 32                        // rows per block
#define RT 2                        // row tiles per wave (MT/16)
#define CPW 4                        // coltiles per wave (16 coltiles / 4 waves)
#define GATE_STRIDE (16 * 16 * 64 * 8)   // halves per packed gate

typedef _Float16 half8 __attribute__((ext_vector_type(8)));
typedef _Float16 half4_t __attribute__((ext_vector_type(4)));
typedef _Float16 half2_t __attribute__((ext_vector_type(2)));
typedef float floatx4 __attribute__((ext_vector_type(4)));

// LDS layout for lx/lh: row-major [MT][256] halves, 8-half-chunk XOR swizzle
__device__ __forceinline__ int lidx(int m, int c) {
    return m * 256 + ((((c >> 3) ^ (m & 7)) << 3)) + (c & 7);
}

// Workgroup barrier that waits only on LDS ops (lgkmcnt), NOT vmcnt -- keeps
// prefetched global loads in flight across phase boundaries. All cross-wave
// hazards at these points are LDS-only, so this is sufficient.
__device__ __forceinline__ void barrier_lgkm() {
    __builtin_amdgcn_sched_barrier(0);
    asm volatile("s_waitcnt lgkmcnt(0)" ::: "memory");
    __builtin_amdgcn_s_barrier();
    __builtin_amdgcn_sched_barrier(0);
}

// ---------- weight packing: B-fragment layout for mfma_f32_16x16x32_f16 ----
// frag (gate g, coltile ct, ktile s): lane holds B[k=s*32+(lane>>4)*8+j][n=ct*16+(lane&15)]
__global__ __launch_bounds__(256) void pack_weights_kernel(
    const float* __restrict__ Wz, const float* __restrict__ Uz,
    const float* __restrict__ Wr, const float* __restrict__ Ur,
    const float* __restrict__ Wh, const float* __restrict__ Uh,
    _Float16* __restrict__ packed)
{
    int tid = blockIdx.x * blockDim.x + threadIdx.x;  // 0..49151
    int lane = tid & 63;
    int s    = (tid >> 6) & 15;
    int ct   = (tid >> 10) & 15;
    int g    = tid >> 14;  // 0:z 1:r 2:h
    const float* W = (g == 0) ? Wz : (g == 1) ? Wr : Wh;
    const float* U = (g == 0) ? Uz : (g == 1) ? Ur : Uh;
    int n  = ct * 16 + (lane & 15);
    int k0 = s * 32 + (lane >> 4) * 8;
    half8 v;
#pragma unroll
    for (int j = 0; j < 8; ++j) {
        int k = k0 + j;
        float f = (k < 256) ? W[k * 256 + n] : U[(k - 256) * 256 + n];
        v[j] = (_Float16)f;
    }
    *reinterpret_cast<half8*>(packed + (size_t)tid * 8) = v;
}

// fragment load for (gate base, coltile ct, ktile s)
#define WFRAG(base, ct, s) \
    (*reinterpret_cast<const half8*>((base) + (size_t)((((ct) * 16 + (s)) * 64 + lane) * 8)))

// ---------- main fused GRU kernel ----------
__global__ __launch_bounds__(256, 2) void gru_main_kernel(
    const float* __restrict__ x, const float* __restrict__ h,
    const _Float16* __restrict__ wpack,
    const float* __restrict__ bz, const float* __restrict__ br,
    const float* __restrict__ bh,
    float* __restrict__ out)
{
    // 32 KB: lx[32*256] + lh[32*256] halves -> 4 blocks/CU by LDS
    __shared__ __align__(16) _Float16 lsm[MT * 256 * 2];
    _Float16* lx = lsm;
    _Float16* lh = lsm + MT * 256;

    const int tid  = threadIdx.x;
    const int lane = tid & 63;
    const int wave = tid >> 6;        // 0..3, owns coltiles wave*4 .. wave*4+3
    const int row0 = blockIdx.x * MT;
    const int m_lo = lane & 15;
    const int quad = lane >> 4;
    const int mx   = m_lo & 7;
    const int ct0  = wave * CPW;

    const _Float16* wz = wpack;
    const _Float16* wr = wpack + GATE_STRIDE;
    const _Float16* wh = wpack + 2 * GATE_STRIDE;

    // ---- prefetch micro-step 0 weight frags (coltile pair 0): in flight
    //      under the staging HBM loads and across the lgkm-only barrier ----
    // dbuf indexed by pair parity p: consume [p], load [p^1].
    half8 wzb[2][2], wrb[2][2];
    wzb[0][0] = WFRAG(wz, ct0 + 0, 0);
    wzb[0][1] = WFRAG(wz, ct0 + 1, 0);
    wrb[0][0] = WFRAG(wr, ct0 + 0, 0);
    wrb[0][1] = WFRAG(wr, ct0 + 1, 0);

    // ---- stage x, h -> LDS fp16 (16 outstanding 16B loads/thread) ----
    {
        const float4* xv = reinterpret_cast<const float4*>(x + (size_t)row0 * NHID);
        const float4* hv = reinterpret_cast<const float4*>(h + (size_t)row0 * NHID);
#pragma unroll
        for (int it = 0; it < (MT * 64) / 256; ++it) {
            int i = it * 256 + tid;
            int m = i >> 6;
            int c = (i & 63) * 4;
            float4 a = xv[i];
            float4 b = hv[i];
            half4_t va = { (_Float16)a.x, (_Float16)a.y, (_Float16)a.z, (_Float16)a.w };
            half4_t vb = { (_Float16)b.x, (_Float16)b.y, (_Float16)b.z, (_Float16)b.w };
            *reinterpret_cast<half4_t*>(&lx[lidx(m, c)]) = va;
            *reinterpret_cast<half4_t*>(&lh[lidx(m, c)]) = vb;
        }
    }
    barrier_lgkm();

    // packed (z*h, 1-z) per output element, fp16x2 (8 VGPRs, built in pass 2)
    half2_t zpk[CPW][RT][4];

    // ---- pass 1: Sz = [x|h]@[Wz;Uz], Sr = [x|h]@[Wr;Ur]  (K=512) ----
    // 32 micro-steps (s,p): each = {prefetch next pair's 4 frags, 8 MFMAs}.
    floatx4 accz[CPW][RT];
    floatx4 accr[CPW][RT];
#pragma unroll
    for (int c = 0; c < CPW; ++c)
#pragma unroll
        for (int rt = 0; rt < RT; ++rt) {
            accz[c][rt] = (floatx4){0.f, 0.f, 0.f, 0.f};
            accr[c][rt] = (floatx4){0.f, 0.f, 0.f, 0.f};
        }

#pragma unroll
    for (int s = 0; s < 16; ++s) {
        const _Float16* asrc = (s < 8) ? lx : lh;
        const int kcx = (((s & 7) * 4 + quad) ^ mx) << 3;
        half8 af[RT];
#pragma unroll
        for (int rt = 0; rt < RT; ++rt)
            af[rt] = *reinterpret_cast<const half8*>(&asrc[(rt * 16 + m_lo) * 256 + kcx]);
#pragma unroll
        for (int p = 0; p < 2; ++p) {
            const int u = s * 2 + p;               // micro-step 0..31
            if (u < 31) {
                const int ns = (p == 1) ? s + 1 : s;
                const int nc = ct0 + (p ^ 1) * 2;  // next pair's coltile base
                wzb[p ^ 1][0] = WFRAG(wz, nc + 0, ns);
                wzb[p ^ 1][1] = WFRAG(wz, nc + 1, ns);
                wrb[p ^ 1][0] = WFRAG(wr, nc + 0, ns);
                wrb[p ^ 1][1] = WFRAG(wr, nc + 1, ns);
            }
            __builtin_amdgcn_s_setprio(1);
#pragma unroll
            for (int q = 0; q < 2; ++q) {
                const int c = p * 2 + q;
#pragma unroll
                for (int rt = 0; rt < RT; ++rt) {
                    accz[c][rt] = __builtin_amdgcn_mfma_f32_16x16x32_f16(af[rt], wzb[p][q], accz[c][rt], 0, 0, 0);
                    accr[c][rt] = __builtin_amdgcn_mfma_f32_16x16x32_f16(af[rt], wrb[p][q], accr[c][rt], 0, 0, 0);
                }
            }
            __builtin_amdgcn_s_setprio(0);
        }
    }

    // ---- prefetch pass-2 micro-step-0 weights + all biases: issued before
    //      the barrier, stay in flight until first use at pass-2 s=0 ----
    half8 whb[2][2];
    whb[0][0] = WFRAG(wh, ct0 + 0, 0);
    whb[0][1] = WFRAG(wh, ct0 + 1, 0);
    float bzv[CPW], brv[CPW], bhv[CPW];
#pragma unroll
    for (int c = 0; c < CPW; ++c) {
        const int col = (ct0 + c) * 16 + m_lo;
        bzv[c] = bz[col];
        brv[c] = br[col];
        bhv[c] = bh[col];
    }

    barrier_lgkm();  // all waves done reading lh (pass 1) before r*h RMW

    // ---- pass 2: Sh = [x|r*h]@[Wh;Uh] (K=512), with epilogue-1 FUSED into
    //      s=0..7 (4 elements/step): z,r sigmoids + lh <- r*h + zpk, placed
    //      under the MFMA clusters. Visibility: s==8 barrier (unchanged). ----
    floatx4 acch[CPW][RT];
#pragma unroll
    for (int c = 0; c < CPW; ++c)
#pragma unroll
        for (int rt = 0; rt < RT; ++rt)
            acch[c][rt] = (floatx4){0.f, 0.f, 0.f, 0.f};

#pragma unroll
    for (int s = 0; s < 16; ++s) {
        if (s == 8) barrier_lgkm();  // all epilogue-1 lh (r*h) writes visible
        const _Float16* asrc = (s < 8) ? lx : lh;
        const int kcx = (((s & 7) * 4 + quad) ^ mx) << 3;
        half8 af[RT];
#pragma unroll
        for (int rt = 0; rt < RT; ++rt)
            af[rt] = *reinterpret_cast<const half8*>(&asrc[(rt * 16 + m_lo) * 256 + kcx]);

        // fused epilogue-1 slice: (c,rt) = (s>>1, s&1), elements e=0..3.
        // C layout: col(tile) = lane&15, row(tile) = quad*4 + reg.
        // Each (row,col) is exclusively owned by this wave (its coltiles),
        // so the lh RMW races with nobody; cross-wave reads wait at s==8.
        if (s < 8) {
            const int ec = s >> 1, ert = s & 1;
            const int col = (ct0 + ec) * 16 + m_lo;
#pragma unroll
            for (int e = 0; e < 4; ++e) {
                const int row = ert * 16 + quad * 4 + e;
                float sz = accz[ec][ert][e] + bzv[ec];
                float sr = accr[ec][ert][e] + brv[ec];
                float zv = 1.f / (1.f + __expf(-sz));
                float rv = 1.f / (1.f + __expf(-sr));
                const int li = lidx(row, col);
                float hval = (float)lh[li];
                lh[li] = (_Float16)(rv * hval);
                zpk[ec][ert][e] = half2_t{ (_Float16)(zv * hval), (_Float16)(1.f - zv) };
            }
        }

#pragma unroll
        for (int p = 0; p < 2; ++p) {
            const int u = s * 2 + p;
            if (u < 31) {
                const int ns = (p == 1) ? s + 1 : s;
                const int nc = ct0 + (p ^ 1) * 2;
                whb[p ^ 1][0] = WFRAG(wh, nc + 0, ns);
                whb[p ^ 1][1] = WFRAG(wh, nc + 1, ns);
            }
            __builtin_amdgcn_s_setprio(1);
#pragma unroll
            for (int q = 0; q < 2; ++q) {
                const int c = p * 2 + q;
#pragma unroll
                for (int rt = 0; rt < RT; ++rt)
                    acch[c][rt] = __builtin_amdgcn_mfma_f32_16x16x32_f16(af[rt], whb[p][q], acch[c][rt], 0, 0, 0);
            }
            __builtin_amdgcn_s_setprio(0);
        }
    }

    // ---- epilogue 2: h_t = z*h + (1-z)*tanh(Sh+bh), direct global stores ----
    // No barrier: nothing after this touches LDS. 16-lane groups write
    // contiguous 64 B segments (NT vs plain measured identical WRITE_SIZE).
    const size_t OUT2 = (size_t)B_ROWS * NHID;
#pragma unroll
    for (int c = 0; c < CPW; ++c) {
        const int col = (ct0 + c) * 16 + m_lo;
#pragma unroll
        for (int rt = 0; rt < RT; ++rt) {
#pragma unroll
            for (int e = 0; e < 4; ++e) {
                const int row = rt * 16 + quad * 4 + e;
                float sh = acch[c][rt][e] + bhv[c];
                float e2 = __expf(2.f * sh);
                float hh = 1.f - 2.f / (e2 + 1.f);  // tanh
                float zh  = (float)zpk[c][rt][e][0];
                float omz = (float)zpk[c][rt][e][1];
                float ht  = zh + omz * hh;
                size_t idx = (size_t)(row0 + row) * NHID + col;
                __builtin_nontemporal_store(ht, &out[idx]);
                __builtin_nontemporal_store(ht, &out[OUT2 + idx]);
            }
        }
    }
}

extern "C" void kernel_launch(void* const* d_in, const int* in_sizes, int n_in,
                              void* d_out, int out_size, void* d_ws, size_t ws_size,
                              hipStream_t stream) {
    (void)in_sizes; (void)n_in; (void)out_size; (void)ws_size;
    const float* x  = (const float*)d_in[0];
    const float* h  = (const float*)d_in[1];
    const float* Wz = (const float*)d_in[2];
    const float* Uz = (const float*)d_in[3];
    const float* bz = (const float*)d_in[4];
    const float* Wr = (const float*)d_in[5];
    const float* Ur = (const float*)d_in[6];
    const float* br = (const float*)d_in[7];
    const float* Wh = (const float*)d_in[8];
    const float* Uh = (const float*)d_in[9];
    const float* bh = (const float*)d_in[10];
    float* out = (float*)d_out;
    _Float16* wpack = (_Float16*)d_ws;  // 3*512*256*2 = 768 KB

    pack_weights_kernel<<<192, 256, 0, stream>>>(Wz, Uz, Wr, Ur, Wh, Uh, wpack);
    gru_main_kernel<<<B_ROWS / MT, 256, 0, stream>>>(x, h, wpack, bz, br, bh, out);
}

// Round 8
// 303.235 us; speedup vs baseline: 1.0369x; 1.0025x over previous
//
#include <hip/hip_runtime.h>
#include <hip/hip_fp16.h>

// GRU cell, B=65536, 256 inputs, 256 hidden, fp32 in/out.
// R11: occupancy pass -- the one axis never tested cleanly. All clean builds
// (R3/R5/R8/R9/R10, VGPR 84-128) ran 4 waves/SIMD; the two accidental
// 64-VGPR builds ran 8 waves/SIMD WITH heavy inner-loop spill traffic and
// still landed within 15-40% of clean 4-wave builds. No pipe exceeds 29%;
// all structural overlap levers are falsified (R8 desync neutral, R9
// persistence regressed, R10 epi-fusion neutral). Remaining theory: per-wave
// latency chains (ds_read->MFMA ~120cy, L2 weight loads ~200-400cy, MFMA
// 19.4cy/SIMD) covered by only 4 peer waves -> double TLP to 8.
// Design to fit 64 VGPR honestly (R8's structure needs ~110):
//  - 512 thr, 8 waves, MT=32, CPW=2, RT=2; 32KB LDS -> 4 blocks/CU
//    = 32 waves/CU = 8/SIMD when VGPR<=64 (m69 ladder).
//  - GATE-SEQUENTIAL: three K=512 passes (z, r, h). acc=16, wdbuf=16, af=8.
//  - z kept as 8 VGPR of half2; h captured into 8 VGPR of half2 at the
//    r-epilogue from the same LDS slots it RMWs (lh <- r*h), so epilogue-2
//    needs NO LDS and lh's overwrite doesn't lose h.
//  - pass s==15 slot prefetches the NEXT pass's step-0 weights (flies over
//    the epilogue + lgkm-only barrier).
//  - barriers: stage; pre-r-epi (all z/r af reads of lh done); h-pass s==8
//    (r*h visibility, R8's movable barrier). z->r boundary barrier-free.
// __launch_bounds__(512,4) -> measured VGPR cap 64 (R4 rule). Demand ~56-62
// by design -> expect spill-free. GATE: FETCH ~70-90MB / WRITE ~165MB; a
// FETCH jump >= +40MB means spills -> experiment tainted.
// Retained: lgkm-only barriers, XOR-swizzled LDS, NT stores, setprio.

#define NHID 256
#define B_ROWS 65536
#define MT 32                        // rows per block
#define RT 2                         // row tiles per wave (MT/16)
#define CPW 2                        // coltiles per wave (16 coltiles / 8 waves)
#define GATE_STRIDE (16 * 16 * 64 * 8)   // halves per packed gate

typedef _Float16 half8 __attribute__((ext_vector_type(8)));
typedef _Float16 half4_t __attribute__((ext_vector_type(4)));
typedef _Float16 half2_t __attribute__((ext_vector_type(2)));
typedef float floatx4 __attribute__((ext_vector_type(4)));

// LDS layout for lx/lh: row-major [MT][256] halves, 8-half-chunk XOR swizzle
__device__ __forceinline__ int lidx(int m, int c) {
    return m * 256 + ((((c >> 3) ^ (m & 7)) << 3)) + (c & 7);
}

// Workgroup barrier that waits only on LDS ops (lgkmcnt), NOT vmcnt -- keeps
// prefetched global loads in flight across phase boundaries.
__device__ __forceinline__ void barrier_lgkm() {
    __builtin_amdgcn_sched_barrier(0);
    asm volatile("s_waitcnt lgkmcnt(0)" ::: "memory");
    __builtin_amdgcn_s_barrier();
    __builtin_amdgcn_sched_barrier(0);
}

// ---------- weight packing: B-fragment layout for mfma_f32_16x16x32_f16 ----
// frag (gate g, coltile ct, ktile s): lane holds B[k=s*32+(lane>>4)*8+j][n=ct*16+(lane&15)]
__global__ __launch_bounds__(256) void pack_weights_kernel(
    const float* __restrict__ Wz, const float* __restrict__ Uz,
    const float* __restrict__ Wr, const float* __restrict__ Ur,
    const float* __restrict__ Wh, const float* __restrict__ Uh,
    _Float16* __restrict__ packed)
{
    int tid = blockIdx.x * blockDim.x + threadIdx.x;  // 0..49151
    int lane = tid & 63;
    int s    = (tid >> 6) & 15;
    int ct   = (tid >> 10) & 15;
    int g    = tid >> 14;  // 0:z 1:r 2:h
    const float* W = (g == 0) ? Wz : (g == 1) ? Wr : Wh;
    const float* U = (g == 0) ? Uz : (g == 1) ? Ur : Uh;
    int n  = ct * 16 + (lane & 15);
    int k0 = s * 32 + (lane >> 4) * 8;
    half8 v;
#pragma unroll
    for (int j = 0; j < 8; ++j) {
        int k = k0 + j;
        float f = (k < 256) ? W[k * 256 + n] : U[(k - 256) * 256 + n];
        v[j] = (_Float16)f;
    }
    *reinterpret_cast<half8*>(packed + (size_t)tid * 8) = v;
}

// fragment load for (gate base, coltile ct, ktile s)
#define WFRAG(base, ct, s) \
    (*reinterpret_cast<const half8*>((base) + (size_t)((((ct) * 16 + (s)) * 64 + lane) * 8)))

// ---------- main fused GRU kernel ----------
__global__ __launch_bounds__(512, 4) void gru_main_kernel(
    const float* __restrict__ x, const float* __restrict__ h,
    const _Float16* __restrict__ wpack,
    const float* __restrict__ bz, const float* __restrict__ br,
    const float* __restrict__ bh,
    float* __restrict__ out)
{
    // 32 KB: lx[32*256] + lh[32*256] halves -> 4 blocks/CU (128 of 160 KB)
    __shared__ __align__(16) _Float16 lsm[MT * 256 * 2];
    _Float16* lx = lsm;
    _Float16* lh = lsm + MT * 256;

    const int tid  = threadIdx.x;
    const int lane = tid & 63;
    const int wave = tid >> 6;        // 0..7, owns coltiles wave*2, wave*2+1
    const int row0 = blockIdx.x * MT;
    const int m_lo = lane & 15;
    const int quad = lane >> 4;
    const int mx   = m_lo & 7;
    const int ct0  = wave * CPW;

    const _Float16* wz = wpack;
    const _Float16* wr = wpack + GATE_STRIDE;
    const _Float16* wh = wpack + 2 * GATE_STRIDE;

    // weight double-buffer for the CURRENT gate only: 4 frags = 16 VGPR
    half8 wb[2][CPW];
    wb[0][0] = WFRAG(wz, ct0 + 0, 0);   // z-pass step 0, flies under staging
    wb[0][1] = WFRAG(wz, ct0 + 1, 0);

    // biases (lane-varying by m_lo): 6 VGPR, live whole kernel
    float bzv[CPW], brv[CPW], bhv[CPW];
#pragma unroll
    for (int c = 0; c < CPW; ++c) {
        const int col = (ct0 + c) * 16 + m_lo;
        bzv[c] = bz[col];
        brv[c] = br[col];
        bhv[c] = bh[col];
    }

    // ---- stage x, h -> LDS fp16 (8 outstanding 16B loads/thread) ----
    {
        const float4* xv = reinterpret_cast<const float4*>(x + (size_t)row0 * NHID);
        const float4* hv = reinterpret_cast<const float4*>(h + (size_t)row0 * NHID);
#pragma unroll
        for (int it = 0; it < (MT * 64) / 512; ++it) {   // 4 iters
            int i = it * 512 + tid;
            int m = i >> 6;
            int c = (i & 63) * 4;
            float4 a = xv[i];
            float4 b = hv[i];
            half4_t va = { (_Float16)a.x, (_Float16)a.y, (_Float16)a.z, (_Float16)a.w };
            half4_t vb = { (_Float16)b.x, (_Float16)b.y, (_Float16)b.z, (_Float16)b.w };
            *reinterpret_cast<half4_t*>(&lx[lidx(m, c)]) = va;
            *reinterpret_cast<half4_t*>(&lh[lidx(m, c)]) = vb;
        }
    }
    barrier_lgkm();

    floatx4 acc[CPW][RT];   // reused by all three passes: 16 VGPR

    // ================= pass Z: Sz = [x|h]@[Wz;Uz] =================
#pragma unroll
    for (int c = 0; c < CPW; ++c)
#pragma unroll
        for (int rt = 0; rt < RT; ++rt)
            acc[c][rt] = (floatx4){0.f, 0.f, 0.f, 0.f};

#pragma unroll
    for (int s = 0; s < 16; ++s) {
        const _Float16* asrc = (s < 8) ? lx : lh;
        const int kcx = (((s & 7) * 4 + quad) ^ mx) << 3;
        half8 af[RT];
#pragma unroll
        for (int rt = 0; rt < RT; ++rt)
            af[rt] = *reinterpret_cast<const half8*>(&asrc[(rt * 16 + m_lo) * 256 + kcx]);
        if (s < 15) {   // prefetch next step; at s==15 prefetch r-pass step 0
            wb[(s + 1) & 1][0] = WFRAG(wz, ct0 + 0, s + 1);
            wb[(s + 1) & 1][1] = WFRAG(wz, ct0 + 1, s + 1);
        } else {
            wb[0][0] = WFRAG(wr, ct0 + 0, 0);   // (15+1)&1 == 0
            wb[0][1] = WFRAG(wr, ct0 + 1, 0);
        }
        __builtin_amdgcn_s_setprio(1);
#pragma unroll
        for (int c = 0; c < CPW; ++c)
#pragma unroll
            for (int rt = 0; rt < RT; ++rt)
                acc[c][rt] = __builtin_amdgcn_mfma_f32_16x16x32_f16(af[rt], wb[s & 1][c], acc[c][rt], 0, 0, 0);
        __builtin_amdgcn_s_setprio(0);
    }

    // ---- epilogue Z (pure registers, NO barrier): z -> 8 VGPR half2 ----
    half2_t zreg[CPW][RT][2];
#pragma unroll
    for (int c = 0; c < CPW; ++c)
#pragma unroll
        for (int rt = 0; rt < RT; ++rt)
#pragma unroll
            for (int e = 0; e < 4; ++e) {
                float sz = acc[c][rt][e] + bzv[c];
                float zv = 1.f / (1.f + __expf(-sz));
                zreg[c][rt][e >> 1][e & 1] = (_Float16)zv;
            }

    // ================= pass R: Sr = [x|h]@[Wr;Ur] =================
    // No barrier vs pass Z: af reads of lx/lh are read-read.
#pragma unroll
    for (int c = 0; c < CPW; ++c)
#pragma unroll
        for (int rt = 0; rt < RT; ++rt)
            acc[c][rt] = (floatx4){0.f, 0.f, 0.f, 0.f};

#pragma unroll
    for (int s = 0; s < 16; ++s) {
        const _Float16* asrc = (s < 8) ? lx : lh;
        const int kcx = (((s & 7) * 4 + quad) ^ mx) << 3;
        half8 af[RT];
#pragma unroll
        for (int rt = 0; rt < RT; ++rt)
            af[rt] = *reinterpret_cast<const half8*>(&asrc[(rt * 16 + m_lo) * 256 + kcx]);
        if (s < 15) {
            wb[(s + 1) & 1][0] = WFRAG(wr, ct0 + 0, s + 1);
            wb[(s + 1) & 1][1] = WFRAG(wr, ct0 + 1, s + 1);
        } else {
            wb[0][0] = WFRAG(wh, ct0 + 0, 0);   // h-pass step 0, flies over
            wb[0][1] = WFRAG(wh, ct0 + 1, 0);   // the barrier + epilogue R
        }
        __builtin_amdgcn_s_setprio(1);
#pragma unroll
        for (int c = 0; c < CPW; ++c)
#pragma unroll
            for (int rt = 0; rt < RT; ++rt)
                acc[c][rt] = __builtin_amdgcn_mfma_f32_16x16x32_f16(af[rt], wb[s & 1][c], acc[c][rt], 0, 0, 0);
        __builtin_amdgcn_s_setprio(0);
    }

    barrier_lgkm();  // all waves' z+r af reads of lh done before r*h RMW

    // ---- epilogue R: lh <- r*h (in-place, wave-exclusive cols); h -> hreg.
    //      C layout: col(tile) = lane&15, row(tile) = quad*4 + reg. ----
    half2_t hreg[CPW][RT][2];
#pragma unroll
    for (int c = 0; c < CPW; ++c) {
        const int col = (ct0 + c) * 16 + m_lo;
#pragma unroll
        for (int rt = 0; rt < RT; ++rt)
#pragma unroll
            for (int e = 0; e < 4; ++e) {
                const int row = rt * 16 + quad * 4 + e;
                float sr = acc[c][rt][e] + brv[c];
                float rv = 1.f / (1.f + __expf(-sr));
                const int li = lidx(row, col);
                _Float16 hval = lh[li];
                lh[li] = (_Float16)(rv * (float)hval);
                hreg[c][rt][e >> 1][e & 1] = hval;   // exact fp16 copy of h
            }
    }
    // NO barrier here: h-pass s<8 reads only lx; lh barrier is at s==8.

    // ================= pass H: Sh = [x|r*h]@[Wh;Uh] =================
#pragma unroll
    for (int c = 0; c < CPW; ++c)
#pragma unroll
        for (int rt = 0; rt < RT; ++rt)
            acc[c][rt] = (floatx4){0.f, 0.f, 0.f, 0.f};

#pragma unroll
    for (int s = 0; s < 16; ++s) {
        if (s == 8) barrier_lgkm();  // all epilogue-R lh (r*h) writes visible
        const _Float16* asrc = (s < 8) ? lx : lh;
        const int kcx = (((s & 7) * 4 + quad) ^ mx) << 3;
        half8 af[RT];
#pragma unroll
        for (int rt = 0; rt < RT; ++rt)
            af[rt] = *reinterpret_cast<const half8*>(&asrc[(rt * 16 + m_lo) * 256 + kcx]);
        if (s < 15) {
            wb[(s + 1) & 1][0] = WFRAG(wh, ct0 + 0, s + 1);
            wb[(s + 1) & 1][1] = WFRAG(wh, ct0 + 1, s + 1);
        }
        __builtin_amdgcn_s_setprio(1);
#pragma unroll
        for (int c = 0; c < CPW; ++c)
#pragma unroll
            for (int rt = 0; rt < RT; ++rt)
                acc[c][rt] = __builtin_amdgcn_mfma_f32_16x16x32_f16(af[rt], wb[s & 1][c], acc[c][rt], 0, 0, 0);
        __builtin_amdgcn_s_setprio(0);
    }

    // ---- epilogue 2: h_t = z*h + (1-z)*tanh(Sh+bh); NO LDS, no barrier ----
    const size_t OUT2 = (size_t)B_ROWS * NHID;
#pragma unroll
    for (int c = 0; c < CPW; ++c) {
        const int col = (ct0 + c) * 16 + m_lo;
#pragma unroll
        for (int rt = 0; rt < RT; ++rt)
#pragma unroll
            for (int e = 0; e < 4; ++e) {
                const int row = rt * 16 + quad * 4 + e;
                float sh = acc[c][rt][e] + bhv[c];
                float e2 = __expf(2.f * sh);
                float hh = 1.f - 2.f / (e2 + 1.f);  // tanh
                float zf = (float)zreg[c][rt][e >> 1][e & 1];
                float hf = (float)hreg[c][rt][e >> 1][e & 1];
                float ht = zf * hf + (1.f - zf) * hh;
                size_t idx = (size_t)(row0 + row) * NHID + col;
                __builtin_nontemporal_store(ht, &out[idx]);
                __builtin_nontemporal_store(ht, &out[OUT2 + idx]);
            }
    }
}

extern "C" void kernel_launch(void* const* d_in, const int* in_sizes, int n_in,
                              void* d_out, int out_size, void* d_ws, size_t ws_size,
                              hipStream_t stream) {
    (void)in_sizes; (void)n_in; (void)out_size; (void)ws_size;
    const float* x  = (const float*)d_in[0];
    const float* h  = (const float*)d_in[1];
    const float* Wz = (const float*)d_in[2];
    const float* Uz = (const float*)d_in[3];
    const float* bz = (const float*)d_in[4];
    const float* Wr = (const float*)d_in[5];
    const float* Ur = (const float*)d_in[6];
    const float* br = (const float*)d_in[7];
    const float* Wh = (const float*)d_in[8];
    const float* Uh = (const float*)d_in[9];
    const float* bh = (const float*)d_in[10];
    float* out = (float*)d_out;
    _Float16* wpack = (_Float16*)d_ws;  // 3*512*256*2 = 768 KB

    pack_weights_kernel<<<192, 256, 0, stream>>>(Wz, Uz, Wr, Ur, Wh, Uh, wpack);
    gru_main_kernel<<<B_ROWS / MT, 512, 0, stream>>>(x, h, wpack, bz, br, bh, out);
}